// Round 13
// baseline (218.776 us; speedup 1.0000x reference)
//
#include <hip/hip_runtime.h>

// De-emphasis IIR: y[n] = x[n] + C*y[n-1] per row, 64 rows of 480000 fp32.
//
// R16 (post-mortem of R13/R15): nt-both-sides was the only real win; dual-
// chain ILP ~null. Remaining theory: TRAFFIC, not throughput. nt loads
// removed cache retention, so R15's 1.4x halo read-amplification all goes
// to HBM: ~292 MB real traffic in ~70us = 4.2 TB/s -- already 2/3 of the
// copy ceiling. Attack the wasted bytes:
//   1) P_OUT=15 (halo amp 17/15 = 1.13x) with the validated dual-chain.
//   2) MIXED loads: nt ONLY for the never-reused middle passes (2..14);
//      normal caching loads for passes 0,1 (this item's halo = prev item's
//      tail) and 15,16 (this item's tail = next item's halo). First toucher
//      populates L2, second hits. Shared regions ~2MB/XCD < 4MB L2; nt bulk
//      (evict-first) won't displace them.
//   3) XCD-aware block swizzle (bijective, 1000%8==0): the 1/4 of halo-
//      sharing pairs that cross blocks land on the same XCD's L2 (the other
//      3/4 are intra-block already).
//   Stores stay nt (write-allocate pollution was the R13-era loss).
// Pre-commit: flat result -> declare empirical ceiling next round.
//
// Geometry: 8000 independent items (17 passes of 256 elems, SEG=4, 16B/lane
// coalesced); wave g handles items g and g+4000 (32 rows apart). 4000 waves
// = 1000 blocks, no LDS, no barriers. Per chain per pass: 3-fma local scan,
// 6-shfl lane-constant wave scan, Bex via algebra (Bv-l3)*C^-4 (bit-exact 0
// at lane 0, validated R11-R15), B63 via readlane, 2-fma carry chain.
//
// Cross-item carry: 512-elem halo (2 passes); 0.97^512 ~ 1.7e-7 (validated
// R1-R15: absmax 0.0625 = fp32 association noise, threshold 0.4475).
// Exact fill: 125 items/row x 3840 out = 480000; stores unconditional
// in-range; only widx==0 halo loads clamp (contribution zeroed by carry
// reset at p==P_HALO).

#define COEFF 0.97f
#define ROW_LEN 480000
#define SPAN_W 256                          // elems per pass (64 lanes x 4)
#define HALO 512
#define P_HALO 2
#define P_OUT 15
#define P_TOT (P_OUT + P_HALO)              // 17
#define OUT_W (P_OUT * SPAN_W)              // 3840; 125*3840 = 480000 exact
#define WPR (ROW_LEN / OUT_W)               // 125 items per row
#define BLOCK 256
#define WAVES (BLOCK / 64)                  // 4 independent waves per block

typedef float v4f __attribute__((ext_vector_type(4)));

constexpr float fpow(float b, int n) {
    float r = 1.0f;
    for (int i = 0; i < n; ++i) r *= b;
    return r;
}
// wave-scan step factors: C^(4 * 2^k)
constexpr float S0 = fpow(COEFF, 4);
constexpr float S1 = fpow(COEFF, 8);
constexpr float S2 = fpow(COEFF, 16);
constexpr float S3 = fpow(COEFF, 32);
constexpr float S4 = fpow(COEFF, 64);
constexpr float S5 = fpow(COEFF, 128);
constexpr float CP  = fpow(COEFF, SPAN_W);  // C^256 per-pass carry decay
constexpr float C1P = fpow(COEFF, 1);
constexpr float C2P = fpow(COEFF, 2);
constexpr float C3P = fpow(COEFF, 3);
constexpr float C4P = fpow(COEFF, 4);
constexpr float IC4 = 1.0f / fpow(COEFF, 4); // C^-4 exclusive-prefix algebra

__device__ __forceinline__ float bcast63(float v) {
    return __int_as_float(__builtin_amdgcn_readlane(__float_as_int(v), 63));
}

__global__ __launch_bounds__(BLOCK, 8) void deemph_kernel(const float* __restrict__ x,
                                                          float* __restrict__ y,
                                                          int n_rows) {
    const int lane = threadIdx.x & 63;
    const int wave = threadIdx.x >> 6;

    // XCD-aware swizzle (bijective when gridDim%8==0; identity fallback):
    // each XCD gets a contiguous chunk of blocks so halo-sharing neighbors
    // share an L2.
    int bid = blockIdx.x;
    const int nb = gridDim.x;
    if ((nb & 7) == 0) {
        const int q = nb >> 3;
        bid = (bid & 7) * q + (bid >> 3);
    }

    const int gw = bid * WAVES + wave;
    const int n_half = (WPR * n_rows) >> 1;       // 4000; items always even
    if (gw >= n_half) return;                     // wave-uniform (exact grid)

    const int iA = gw;
    const int iB = gw + n_half;                   // always < n_items

    const int rowA = iA / WPR, widxA = iA - rowA * WPR;   // magic-mul div
    const int rowB = iB / WPR, widxB = iB - rowB * WPR;

    const float* __restrict__ xrowA = x + (long long)rowA * ROW_LEN;
    float* __restrict__ yrowA       = y + (long long)rowA * ROW_LEN;
    const float* __restrict__ xrowB = x + (long long)rowB * ROW_LEN;
    float* __restrict__ yrowB       = y + (long long)rowB * ROW_LEN;

    // element base of pass 0 per chain (passes 0,1 = halo; <0 only widx==0)
    const int lbA = widxA * OUT_W - HALO + 4 * lane;
    const int lbB = widxB * OUT_W - HALO + 4 * lane;
    const bool rsA = (widxA == 0);
    const bool rsB = (widxB == 0);

    // Aex = C^(4*lane): exact bit-product, shared by both chains
    float Aex = 1.0f;
    if (lane & 1)  Aex *= S0;
    if (lane & 2)  Aex *= S1;
    if (lane & 4)  Aex *= S2;
    if (lane & 8)  Aex *= S3;
    if (lane & 16) Aex *= S4;
    if (lane & 32) Aex *= S5;

    float cA = 0.0f, cB = 0.0f;   // independent carry chains
    #pragma unroll
    for (int p = 0; p < P_TOT; ++p) {
        const int eA = lbA + p * SPAN_W;
        const int eB = lbB + p * SPAN_W;
        const int ecA = eA < 0 ? 0 : eA;          // halo clamp (values unused)
        const int ecB = eB < 0 ? 0 : eB;

        // Mixed policy: nt for the never-reused middle (p=2..14); NORMAL
        // caching loads for the shared regions (p=0,1 halo; p=15,16 tail,
        // re-read as the next item's halo) so L2 dedups the HBM fetch.
        // p is a constant after full unroll -> the ternary folds.
        const bool ntl = (p > 1) && (p < P_OUT);
        const v4f vA = ntl ? __builtin_nontemporal_load((const v4f*)(xrowA + ecA))
                           : *(const v4f*)(xrowA + ecA);
        const v4f vB = ntl ? __builtin_nontemporal_load((const v4f*)(xrowB + ecB))
                           : *(const v4f*)(xrowB + ecB);

        // local inclusive scans (independent)
        const float a0 = vA.x;
        const float b0 = vB.x;
        const float a1 = fmaf(COEFF, a0, vA.y);
        const float b1 = fmaf(COEFF, b0, vB.y);
        const float a2 = fmaf(COEFF, a1, vA.z);
        const float b2 = fmaf(COEFF, b1, vB.z);
        const float a3 = fmaf(COEFF, a2, vA.w);
        const float b3 = fmaf(COEFF, b2, vB.w);

        // dual wave scans, steps interleaved (independent DS chains)
        float BA = a3, BB = b3, pA, pB;
        pA = __shfl_up(BA, 1);  pB = __shfl_up(BB, 1);
        if (lane >= 1)  { BA = fmaf(S0, pA, BA); BB = fmaf(S0, pB, BB); }
        pA = __shfl_up(BA, 2);  pB = __shfl_up(BB, 2);
        if (lane >= 2)  { BA = fmaf(S1, pA, BA); BB = fmaf(S1, pB, BB); }
        pA = __shfl_up(BA, 4);  pB = __shfl_up(BB, 4);
        if (lane >= 4)  { BA = fmaf(S2, pA, BA); BB = fmaf(S2, pB, BB); }
        pA = __shfl_up(BA, 8);  pB = __shfl_up(BB, 8);
        if (lane >= 8)  { BA = fmaf(S3, pA, BA); BB = fmaf(S3, pB, BB); }
        pA = __shfl_up(BA, 16); pB = __shfl_up(BB, 16);
        if (lane >= 16) { BA = fmaf(S4, pA, BA); BB = fmaf(S4, pB, BB); }
        pA = __shfl_up(BA, 32); pB = __shfl_up(BB, 32);
        if (lane >= 32) { BA = fmaf(S5, pA, BA); BB = fmaf(S5, pB, BB); }

        // exclusive prefix by algebra (lane 0 bit-exact 0); totals via VALU
        const float BexA = (BA - a3) * IC4;
        const float BexB = (BB - b3) * IC4;
        const float B63A = bcast63(BA);
        const float B63B = bcast63(BB);

        float ccA = cA, ccB = cB;
        if (p == P_HALO) {                         // row start: carry = 0
            if (rsA) ccA = 0.0f;
            if (rsB) ccB = 0.0f;
        }
        const float KtA = fmaf(ccA, Aex, BexA);
        const float KtB = fmaf(ccB, Aex, BexB);
        cA = fmaf(ccA, CP, B63A);                  // 2-fma/pass carry chains
        cB = fmaf(ccB, CP, B63B);

        if (p >= P_HALO) {
            v4f oA, oB;
            oA.x = fmaf(KtA, C1P, a0);  oB.x = fmaf(KtB, C1P, b0);
            oA.y = fmaf(KtA, C2P, a1);  oB.y = fmaf(KtB, C2P, b1);
            oA.z = fmaf(KtA, C3P, a2);  oB.z = fmaf(KtB, C3P, b2);
            oA.w = fmaf(KtA, C4P, a3);  oB.w = fmaf(KtB, C4P, b3);
            __builtin_nontemporal_store(oA, (v4f*)(yrowA + eA));
            __builtin_nontemporal_store(oB, (v4f*)(yrowB + eB));
        }
    }
}

extern "C" void kernel_launch(void* const* d_in, const int* in_sizes, int n_in,
                              void* d_out, int out_size, void* d_ws, size_t ws_size,
                              hipStream_t stream) {
    (void)n_in; (void)d_ws; (void)ws_size; (void)out_size;
    const float* x = (const float*)d_in[0];
    float* y = (float*)d_out;
    const int n_rows  = in_sizes[0] / ROW_LEN;         // 64 for (32,2,480000)
    const int n_half  = (WPR * n_rows) / 2;            // 4000
    const int nblocks = (n_half + WAVES - 1) / WAVES;  // 1000 exact
    deemph_kernel<<<dim3(nblocks), BLOCK, 0, stream>>>(x, y, n_rows);
}